// Round 6
// baseline (370.215 us; speedup 1.0000x reference)
//
#include <hip/hip_runtime.h>

typedef unsigned short u16;
typedef unsigned int   u32;
typedef short bf16x8 __attribute__((ext_vector_type(8)));
typedef float f32x4  __attribute__((ext_vector_type(4)));

__device__ __forceinline__ float bf_lo(u32 u){ return __uint_as_float(u << 16); }
__device__ __forceinline__ float bf_hi(u32 u){ return __uint_as_float(u & 0xffff0000u); }
__device__ __forceinline__ u16 bf16r(float f){
  u32 u = __float_as_uint(f);
  u += 0x7fffu + ((u >> 16) & 1u);
  return (u16)(u >> 16);
}
__device__ __forceinline__ u32 pack2(float a, float b){
  return (u32)bf16r(a) | ((u32)bf16r(b) << 16);
}
// truncating bf16 pair-pack (relative err 2^-8, fine for P in [0,1])
__device__ __forceinline__ u32 pk_trunc(float a, float b){
  return (__float_as_uint(a) >> 16) | (__float_as_uint(b) & 0xffff0000u);
}
__device__ __forceinline__ float gelu_f(float x){
  float t = 0.7978845608028654f * (x + 0.044715f * x * x * x);
  t = fminf(fmaxf(t, -12.f), 12.f);
  float e = __expf(2.f * t);
  float th = (e - 1.f) / (e + 1.f);
  return 0.5f * x * (1.f + th);
}
// async global->LDS, 16B/lane; LDS dest = wave-uniform base + lane*16 (m104)
__device__ __forceinline__ void glds16(const void* g, void* l) {
  __builtin_amdgcn_global_load_lds(
      (const __attribute__((address_space(1))) void*)g,
      (__attribute__((address_space(3))) void*)l, 16, 0, 0);
}

#define QSCALE 0.1803368801111204f   /* 0.125 * log2(e): scores in exp2 domain */

// ---------------- prep bodies (merged into one dispatch) --------------------
__device__ __forceinline__ void wt_body(const float* __restrict__ W,
                                        u16* __restrict__ Wt, int K, int N,
                                        int kx, int nx) {
  __shared__ float t[32][33];
  int k0 = kx * 32, n0 = nx * 32;
  int tx = threadIdx.x & 31, ty = threadIdx.x >> 5;
  #pragma unroll
  for (int i = 0; i < 32; i += 8)
    t[ty + i][tx] = W[(size_t)(k0 + ty + i) * N + n0 + tx];
  __syncthreads();
  #pragma unroll
  for (int i = 0; i < 32; i += 8)
    Wt[(size_t)(n0 + ty + i) * K + k0 + tx] = bf16r(t[tx][ty + i]);
}

__device__ __forceinline__ void ln_body(const float* __restrict__ x,
                                        const float* __restrict__ g,
                                        const float* __restrict__ bta,
                                        u16* __restrict__ out, int row) {
  int tid = threadIdx.x;
  const float4 xv = ((const float4*)(x + (size_t)row * 1024))[tid];
  float s = xv.x + xv.y + xv.z + xv.w;
  float q = xv.x*xv.x + xv.y*xv.y + xv.z*xv.z + xv.w*xv.w;
  #pragma unroll
  for (int off = 32; off > 0; off >>= 1) {
    s += __shfl_down(s, off);
    q += __shfl_down(q, off);
  }
  __shared__ float ss[4], sq[4];
  if ((tid & 63) == 0) { ss[tid >> 6] = s; sq[tid >> 6] = q; }
  __syncthreads();
  s = ss[0] + ss[1] + ss[2] + ss[3];
  q = sq[0] + sq[1] + sq[2] + sq[3];
  float mu = s * (1.f/1024.f);
  float rs = rsqrtf(q * (1.f/1024.f) - mu*mu + 1e-5f);
  const float4 gv = ((const float4*)g)[tid];
  const float4 bv = ((const float4*)bta)[tid];
  uint2 o;
  o.x = pack2((xv.x-mu)*rs*gv.x + bv.x, (xv.y-mu)*rs*gv.y + bv.y);
  o.y = pack2((xv.z-mu)*rs*gv.z + bv.z, (xv.w-mu)*rs*gv.w + bv.w);
  ((uint2*)(out + (size_t)row * 1024))[tid] = o;
}

// all 4 weight transposes + LN1 in one flat-grid dispatch
__global__ __launch_bounds__(256) void prep_k(
    const float* __restrict__ w_attn, const float* __restrict__ w_proj,
    const float* __restrict__ w_fc,   const float* __restrict__ w_fc2,
    u16* __restrict__ wt_attn, u16* __restrict__ wt_proj,
    u16* __restrict__ wt_fc,   u16* __restrict__ wt_fc2,
    const float* __restrict__ x, const float* __restrict__ g,
    const float* __restrict__ b, u16* __restrict__ h1)
{
  int i = blockIdx.x;
  if (i < 3072)       wt_body(w_attn, wt_attn, 1024, 3072, i & 31, i >> 5);
  else if (i < 4096)  { int j = i - 3072; wt_body(w_proj, wt_proj, 1024, 1024, j & 31, j >> 5); }
  else if (i < 8192)  { int j = i - 4096; wt_body(w_fc,   wt_fc,   1024, 4096, j & 31, j >> 5); }
  else if (i < 12288) { int j = i - 8192; wt_body(w_fc2,  wt_fc2,  4096, 1024, j & 127, j >> 7); }
  else                ln_body(x, g, b, h1, i - 12288);
}

// ---------------- layernorm (standalone, for LN2) ---------------------------
__global__ __launch_bounds__(256) void ln_k(const float* __restrict__ x,
                                            const float* __restrict__ g,
                                            const float* __restrict__ bta,
                                            u16* __restrict__ out) {
  ln_body(x, g, bta, out, blockIdx.x);
}

// ---------------- GEMM: C = A[M,K(lda)]bf16 @ Bt[N,K(lda)]^T + epilogue -----
// Single-buffered 2-barrier K-loop (R9-proven). MI=4 (TM=128) for big GEMMs,
// MI=2 for N=1024 GEMMs. XCD-chunked block swizzle (T1): HW maps dispatch-id
// %8 -> XCD, so logical = (orig%8)*(nwg/8)+orig/8 gives each XCD a contiguous
// tile range (same-XCD blocks share B panels -> L2 reuse). Bijective iff
// nwg%8==0 (all our grids: 1024/768/512/512); identity fallback otherwise.
// MODE 0: bf16=v+b  1/3: f32=v+b+resid  2: bf16=gelu(v+b)
// MODE 4: qkv fused epilogue -- cols<1024: bf16=(v+b)*QSCALE -> out;
//         cols 1024..2047 (K): bf16=v+b -> out; cols>=2048 (V): write
//         TRANSPOSED to vtb[(t>>11)*1024 + (col-2048)][t&2047] (packed 8B).
// MODE 5: split-K partial bf16
template<int MODE, int MI, int LB>
__global__ __launch_bounds__(256, LB) void gemm_k(
    const u16* __restrict__ A, const u16* __restrict__ Bt,
    const float* __restrict__ bias, const float* __restrict__ resid,
    void* __restrict__ out, int M, int N, int K, int lda,
    u16* __restrict__ vtb)
{
  constexpr int TM = MI * 32;
  __shared__ u16 Al[TM * 64];
  __shared__ u16 Bl[128 * 64];
  const int tid = threadIdx.x;
  // XCD-chunked swizzle
  const int gx = gridDim.x;
  const int nwg = gx * gridDim.y;
  const int orig = blockIdx.y * gx + blockIdx.x;
  const int lg = ((nwg & 7) == 0) ? ((orig & 7) * (nwg >> 3) + (orig >> 3))
                                  : orig;
  const int bx  = lg % gx;
  const int byl = lg / gx;
  const int sp = (MODE == 5) ? (byl >> 3) : 0;
  const int n0 = (MODE == 5) ? ((byl & 7) * 128) : (byl * 128);
  const size_t koff = (size_t)sp * K;
  const int m0 = bx * TM;
  const int wave = tid >> 6, lane = tid & 63;
  const int wm = (wave >> 1) * (MI * 16), wn = (wave & 1) * 64;
  const int l15 = lane & 15, quad = lane >> 4;
  const int sr = lane >> 3, cs = lane & 7;
  f32x4 acc[MI][4];
  const f32x4 zero = {0.f, 0.f, 0.f, 0.f};
  #pragma unroll
  for (int i = 0; i < MI; ++i)
    #pragma unroll
    for (int j = 0; j < 4; ++j)
      acc[i][j] = zero;
  for (int k0 = 0; k0 < K; k0 += 64) {
    __syncthreads();
    #pragma unroll
    for (int it = 0; it < MI; ++it) {
      int r = it*32 + wave*8 + sr;
      int c = cs ^ (r & 7);
      glds16(&A[(size_t)(m0 + r) * lda + koff + k0 + c*8], &Al[(it*32 + wave*8) * 64]);
    }
    #pragma unroll
    for (int it = 0; it < 4; ++it) {
      int r = it*32 + wave*8 + sr;
      int c = cs ^ (r & 7);
      glds16(&Bt[(size_t)(n0 + r) * lda + koff + k0 + c*8], &Bl[(it*32 + wave*8) * 64]);
    }
    __syncthreads();
    #pragma unroll
    for (int kk = 0; kk < 2; ++kk) {
      bf16x8 af[MI], bfr[4];
      #pragma unroll
      for (int i = 0; i < MI; ++i) {
        int R = wm + i*16 + l15;
        af[i] = *(const bf16x8*)&Al[R*64 + ((kk*4 + quad) ^ (R & 7)) * 8];
      }
      #pragma unroll
      for (int j = 0; j < 4; ++j) {
        int R = wn + j*16 + l15;
        bfr[j] = *(const bf16x8*)&Bl[R*64 + ((kk*4 + quad) ^ (R & 7)) * 8];
      }
      #pragma unroll
      for (int i = 0; i < MI; ++i)
        #pragma unroll
        for (int j = 0; j < 4; ++j)
          acc[i][j] = __builtin_amdgcn_mfma_f32_16x16x32_bf16(af[i], bfr[j], acc[i][j], 0, 0, 0);
    }
  }
  #pragma unroll
  for (int i = 0; i < MI; ++i) {
    #pragma unroll
    for (int j = 0; j < 4; ++j) {
      int col = n0 + wn + j*16 + l15;
      float bv = (MODE == 5) ? 0.f : bias[col];
      if constexpr (MODE == 4) {
        if (col >= 2048) {              // V: write transposed to Vt, packed 8B
          int t0 = m0 + wm + i*16 + quad*4;
          size_t vidx = ((size_t)((t0 >> 11)*1024 + (col - 2048)))*2048 + (t0 & 2047);
          uint2 pw;
          pw.x = pack2(acc[i][j][0] + bv, acc[i][j][1] + bv);
          pw.y = pack2(acc[i][j][2] + bv, acc[i][j][3] + bv);
          *(uint2*)&vtb[vidx] = pw;
          continue;
        }
      }
      float sc = (MODE == 4 && col < 1024) ? QSCALE : 1.0f;
      #pragma unroll
      for (int r = 0; r < 4; ++r) {
        int row = m0 + wm + i*16 + quad*4 + r;
        size_t idx = (size_t)row * N + col;
        float v = acc[i][j][r] + bv;
        if constexpr (MODE == 0)      ((u16*)out)[idx] = bf16r(v);
        else if constexpr (MODE == 1) ((float*)out)[idx] = v + resid[idx];
        else if constexpr (MODE == 2) ((u16*)out)[idx] = bf16r(gelu_f(v));
        else if constexpr (MODE == 4) ((u16*)out)[idx] = bf16r(v * sc);
        else if constexpr (MODE == 5) ((u16*)out)[(size_t)sp*M*N + idx] = bf16r(v);
        else                          ((float*)out)[idx] = v + resid[idx];
      }
    }
  }
}

// ---------------- split-K combine: out = p0 + p1 + bias + x2 (fp32) ---------
__global__ __launch_bounds__(256) void cmb_k(const u16* __restrict__ p,
                                             const float* __restrict__ bias,
                                             const float* __restrict__ x2,
                                             float* __restrict__ out) {
  int row = blockIdx.x, t = threadIdx.x;
  size_t i = (size_t)row * 1024 + t*4;
  uint2 a = *(const uint2*)&p[i];
  uint2 b = *(const uint2*)&p[4194304 + i];
  float4 xv = ((const float4*)x2)[i >> 2];
  float4 bv = ((const float4*)bias)[t];
  float4 o;
  o.x = bf_lo(a.x) + bf_lo(b.x) + bv.x + xv.x;
  o.y = bf_hi(a.x) + bf_hi(b.x) + bv.y + xv.y;
  o.z = bf_lo(a.y) + bf_lo(b.y) + bv.z + xv.z;
  o.w = bf_hi(a.y) + bf_hi(b.y) + bv.w + xv.w;
  ((float4*)out)[i >> 2] = o;
}

// ---------------- MFMA flash attention, S^T, 64-q blocks, fixed-max ---------
// R9-proven shape (grid 1024 = 4 blocks/CU, 64 q/block, heavy-first) with one
// change (R22): V is read DIRECT global->VGPR instead of LDS-staged. The
// kernel is LDS-pipe-bound (22 LDS ops/wave/tile vs ~80cyc of MFMA issue); V's
// LDS layout equals its global layout (Vt pre-transposed by the qkv epilogue)
// and the tile is L2-resident, so the LDS broadcast buys nothing. LDS ops
// drop 22->14, staging glds16 halves, LDS 30->17KB. V loads are issued in the
// staging window so their L2 latency hides under the K-stage vmcnt drain.
__global__ __launch_bounds__(256, 4) void attn_k(const u16* __restrict__ qkv,
                                                 const u16* __restrict__ Vt,
                                                 u16* __restrict__ y) {
  __shared__ u16 Kl[64*64];      // keys x d, XOR-swizzled chunks
  __shared__ u16 Pw[4*16*72];    // per-wave P: 16 q x 64 keys bf16 (+8 pad)
  const int tid = threadIdx.x;
  const int bh = blockIdx.x & 31, bb = bh >> 4, h = bh & 15;
  const int qt = 31 - (int)(blockIdx.x >> 5);   // heavy first
  const int w = tid >> 6, lane = tid & 63;
  const int l15 = lane & 15, quad = lane >> 4;
  const int sr = lane >> 3, cs = lane & 7;
  u16* Pme = Pw + w * (16*72);
  const int w16l = w*16 + l15;
  const int dquad = quad*4;

  const u16* qp = qkv + ((size_t)(bb*2048 + qt*64 + w16l))*3072 + h*64 + quad*8;
  const bf16x8 aq0 = *(const bf16x8*)qp;
  const bf16x8 aq1 = *(const bf16x8*)(qp + 32);

  f32x4 o[4];
  const f32x4 zero = {0.f,0.f,0.f,0.f};
  #pragma unroll
  for (int dt = 0; dt < 4; ++dt) o[dt] = zero;
  float l = 0.f;

  const u16* kbase = qkv + (size_t)bb*2048*3072 + 1024 + h*64;
  const u16* vbase = Vt + (size_t)bh*64*2048;

  for (int kt = 0; kt <= qt; ++kt) {
    __syncthreads();
    #pragma unroll
    for (int it = 0; it < 2; ++it) {
      int r = it*32 + w*8 + sr;
      int c = cs ^ (r & 7);
      glds16(kbase + (size_t)(kt*64 + r)*3072 + c*8, &Kl[(it*32 + w*8) * 64]);
    }
    // V direct loads (no LDS; complete at the barrier's vmcnt drain, latency
    // shared with the K staging above)
    bf16x8 av[4][2];
    #pragma unroll
    for (int dt = 0; dt < 4; ++dt) {
      const u16* vp = vbase + (size_t)(dt*16 + l15)*2048 + kt*64 + quad*8;
      av[dt][0] = *(const bf16x8*)vp;
      av[dt][1] = *(const bf16x8*)(vp + 32);
    }
    __syncthreads();
    bf16x8 ak[4][2];
    #pragma unroll
    for (int nt = 0; nt < 4; ++nt) {
      int R = nt*16 + l15;
      #pragma unroll
      for (int kk = 0; kk < 2; ++kk)
        ak[nt][kk] = *(const bf16x8*)&Kl[R*64 + ((kk*4 + quad) ^ (R & 7)) * 8];
    }
    f32x4 sv[4];
    #pragma unroll
    for (int nt = 0; nt < 4; ++nt) {
      f32x4 s = zero;
      s = __builtin_amdgcn_mfma_f32_16x16x32_bf16(ak[nt][0], aq0, s, 0, 0, 0);
      s = __builtin_amdgcn_mfma_f32_16x16x32_bf16(ak[nt][1], aq1, s, 0, 0, 0);
      sv[nt] = s;
    }
    if (kt == qt) {                           // diagonal tile: causal mask
      #pragma unroll
      for (int nt = 0; nt < 4; ++nt)
        #pragma unroll
        for (int r = 0; r < 4; ++r)
          if (nt*16 + dquad + r > w16l) sv[nt][r] = -1e30f;
    }
    float pv[4][4];
    #pragma unroll
    for (int nt = 0; nt < 4; ++nt)
      #pragma unroll
      for (int r = 0; r < 4; ++r)
        pv[nt][r] = exp2f(sv[nt][r]);         // fixed max=0 (bounded scores)
    l += ((pv[0][0]+pv[0][1])+(pv[0][2]+pv[0][3]))
       + ((pv[1][0]+pv[1][1])+(pv[1][2]+pv[1][3]))
       + ((pv[2][0]+pv[2][1])+(pv[2][2]+pv[2][3]))
       + ((pv[3][0]+pv[3][1])+(pv[3][2]+pv[3][3]));
    #pragma unroll
    for (int nt = 0; nt < 4; ++nt) {
      uint2 pr;
      pr.x = pk_trunc(pv[nt][0], pv[nt][1]);
      pr.y = pk_trunc(pv[nt][2], pv[nt][3]);
      *(uint2*)&Pme[l15*72 + nt*16 + dquad] = pr;
    }
    const bf16x8 bp0 = *(const bf16x8*)&Pme[l15*72 + quad*8];
    const bf16x8 bp1 = *(const bf16x8*)&Pme[l15*72 + 32 + quad*8];
    #pragma unroll
    for (int dt = 0; dt < 4; ++dt) {
      o[dt] = __builtin_amdgcn_mfma_f32_16x16x32_bf16(av[dt][0], bp0, o[dt], 0, 0, 0);
      o[dt] = __builtin_amdgcn_mfma_f32_16x16x32_bf16(av[dt][1], bp1, o[dt], 0, 0, 0);
    }
  }
  float lt = l;
  lt += __shfl_xor(lt, 16);
  lt += __shfl_xor(lt, 32);
  float inv = 1.f / lt;
  u16* yp = y + ((size_t)(bb*2048 + qt*64 + w16l))*1024 + h*64;
  #pragma unroll
  for (int dt = 0; dt < 4; ++dt) {
    uint2 pk;
    pk.x = pack2(o[dt][0]*inv, o[dt][1]*inv);
    pk.y = pack2(o[dt][2]*inv, o[dt][3]*inv);
    *(uint2*)(yp + dt*16 + dquad) = pk;
  }
}

// ---------------------------------------------------------------------------
extern "C" void kernel_launch(void* const* d_in, const int* in_sizes, int n_in,
                              void* d_out, int out_size, void* d_ws, size_t ws_size,
                              hipStream_t stream) {
  const float* x      = (const float*)d_in[0];
  const float* ln1_g  = (const float*)d_in[1];
  const float* ln1_b  = (const float*)d_in[2];
  const float* w_attn = (const float*)d_in[3];
  const float* b_attn = (const float*)d_in[4];
  const float* w_proj = (const float*)d_in[5];
  const float* b_proj = (const float*)d_in[6];
  const float* ln2_g  = (const float*)d_in[7];
  const float* ln2_b  = (const float*)d_in[8];
  const float* w_fc   = (const float*)d_in[9];
  const float* b_fc   = (const float*)d_in[10];
  const float* w_fc2  = (const float*)d_in[11];
  const float* b_fc2  = (const float*)d_in[12];

  char* ws = (char*)d_ws;
  u16*   wt_attn = (u16*)(ws);                 // [3072,1024] bf16 (pk2 alias later)
  u16*   wt_proj = (u16*)(ws + 6291456);       // [1024,1024]
  u16*   wt_fc   = (u16*)(ws + 8388608);       // [4096,1024]
  u16*   wt_fc2  = (u16*)(ws + 16777216);      // [1024,4096]
  u16*   h1      = (u16*)(ws + 25165824);      // [4096,1024] bf16 (h2 alias)
  u16*   qkvb    = (u16*)(ws + 33554432);      // [4096,3072] bf16 (act alias;
                                               //  V third never written/read)
  u16*   yb      = (u16*)(ws + 58720256);      // [4096,1024] bf16
  float* x2      = (float*)(ws + 67108864);    // [4096,1024] f32
  u16*   h2  = h1;
  u16*   vtb = (u16*)(ws + 67108864);          // Vt [32,64,2048] bf16: aliases
                                               //  x2 (dead until proj; proj runs
                                               //  after attn, so clobber is safe)
  u16*   act = qkvb;                           // [4096,4096] bf16
  u16*   pk2 = (u16*)(ws);                     // fc2 partials [2][4096,1024] bf16

  // 4 weight transposes + LN1, one dispatch
  prep_k<<<dim3(16384), 256, 0, stream>>>(w_attn, w_proj, w_fc, w_fc2,
                                          wt_attn, wt_proj, wt_fc, wt_fc2,
                                          x, ln1_g, ln1_b, h1);
  // qkv GEMM with fused V-transpose epilogue
  gemm_k<4,4,3><<<dim3(32, 24), 256, 0, stream>>>(h1, wt_attn, b_attn, nullptr,
      (void*)qkvb, 4096, 3072, 1024, 1024, vtb);
  attn_k<<<dim3(1024), 256, 0, stream>>>(qkvb, vtb, yb);
  gemm_k<1,2,3><<<dim3(64, 8), 256, 0, stream>>>(yb, wt_proj, b_proj, x,
      (void*)x2, 4096, 1024, 1024, 1024, nullptr);
  ln_k<<<4096, 256, 0, stream>>>(x2, ln2_g, ln2_b, h2);
  gemm_k<2,4,3><<<dim3(32, 32), 256, 0, stream>>>(h2, wt_fc, b_fc, nullptr,
      (void*)act, 4096, 4096, 1024, 1024, nullptr);
  // fc2 split-K=2, MI=4 (TM=128): 2x the A-reuse per staged B panel vs MI=2
  gemm_k<5,4,3><<<dim3(32, 16), 256, 0, stream>>>(act, wt_fc2, b_fc2, nullptr,
      (void*)pk2, 4096, 1024, 2048, 4096, nullptr);
  cmb_k<<<4096, 256, 0, stream>>>(pk2, b_fc2, x2, (float*)d_out);
}

// Round 7
// 322.117 us; speedup vs baseline: 1.1493x; 1.1493x over previous
//
#include <hip/hip_runtime.h>

typedef unsigned short u16;
typedef unsigned int   u32;
typedef short bf16x8 __attribute__((ext_vector_type(8)));
typedef float f32x4  __attribute__((ext_vector_type(4)));

__device__ __forceinline__ float bf_lo(u32 u){ return __uint_as_float(u << 16); }
__device__ __forceinline__ float bf_hi(u32 u){ return __uint_as_float(u & 0xffff0000u); }
__device__ __forceinline__ u16 bf16r(float f){
  u32 u = __float_as_uint(f);
  u += 0x7fffu + ((u >> 16) & 1u);
  return (u16)(u >> 16);
}
__device__ __forceinline__ u32 pack2(float a, float b){
  return (u32)bf16r(a) | ((u32)bf16r(b) << 16);
}
// truncating bf16 pair-pack (relative err 2^-8, fine for P in [0,1])
__device__ __forceinline__ u32 pk_trunc(float a, float b){
  return (__float_as_uint(a) >> 16) | (__float_as_uint(b) & 0xffff0000u);
}
__device__ __forceinline__ float gelu_f(float x){
  float t = 0.7978845608028654f * (x + 0.044715f * x * x * x);
  t = fminf(fmaxf(t, -12.f), 12.f);
  float e = __expf(2.f * t);
  float th = (e - 1.f) / (e + 1.f);
  return 0.5f * x * (1.f + th);
}
// async global->LDS, 16B/lane; LDS dest = wave-uniform base + lane*16 (m104)
__device__ __forceinline__ void glds16(const void* g, void* l) {
  __builtin_amdgcn_global_load_lds(
      (const __attribute__((address_space(1))) void*)g,
      (__attribute__((address_space(3))) void*)l, 16, 0, 0);
}

#define QSCALE 0.1803368801111204f   /* 0.125 * log2(e): scores in exp2 domain */

// ---------------- prep bodies (merged into one dispatch) --------------------
__device__ __forceinline__ void wt_body(const float* __restrict__ W,
                                        u16* __restrict__ Wt, int K, int N,
                                        int kx, int nx) {
  __shared__ float t[32][33];
  int k0 = kx * 32, n0 = nx * 32;
  int tx = threadIdx.x & 31, ty = threadIdx.x >> 5;
  #pragma unroll
  for (int i = 0; i < 32; i += 8)
    t[ty + i][tx] = W[(size_t)(k0 + ty + i) * N + n0 + tx];
  __syncthreads();
  #pragma unroll
  for (int i = 0; i < 32; i += 8)
    Wt[(size_t)(n0 + ty + i) * K + k0 + tx] = bf16r(t[tx][ty + i]);
}

__device__ __forceinline__ void ln_body(const float* __restrict__ x,
                                        const float* __restrict__ g,
                                        const float* __restrict__ bta,
                                        u16* __restrict__ out, int row) {
  int tid = threadIdx.x;
  const float4 xv = ((const float4*)(x + (size_t)row * 1024))[tid];
  float s = xv.x + xv.y + xv.z + xv.w;
  float q = xv.x*xv.x + xv.y*xv.y + xv.z*xv.z + xv.w*xv.w;
  #pragma unroll
  for (int off = 32; off > 0; off >>= 1) {
    s += __shfl_down(s, off);
    q += __shfl_down(q, off);
  }
  __shared__ float ss[4], sq[4];
  if ((tid & 63) == 0) { ss[tid >> 6] = s; sq[tid >> 6] = q; }
  __syncthreads();
  s = ss[0] + ss[1] + ss[2] + ss[3];
  q = sq[0] + sq[1] + sq[2] + sq[3];
  float mu = s * (1.f/1024.f);
  float rs = rsqrtf(q * (1.f/1024.f) - mu*mu + 1e-5f);
  const float4 gv = ((const float4*)g)[tid];
  const float4 bv = ((const float4*)bta)[tid];
  uint2 o;
  o.x = pack2((xv.x-mu)*rs*gv.x + bv.x, (xv.y-mu)*rs*gv.y + bv.y);
  o.y = pack2((xv.z-mu)*rs*gv.z + bv.z, (xv.w-mu)*rs*gv.w + bv.w);
  ((uint2*)(out + (size_t)row * 1024))[tid] = o;
}

// all 4 weight transposes + LN1 in one flat-grid dispatch
__global__ __launch_bounds__(256) void prep_k(
    const float* __restrict__ w_attn, const float* __restrict__ w_proj,
    const float* __restrict__ w_fc,   const float* __restrict__ w_fc2,
    u16* __restrict__ wt_attn, u16* __restrict__ wt_proj,
    u16* __restrict__ wt_fc,   u16* __restrict__ wt_fc2,
    const float* __restrict__ x, const float* __restrict__ g,
    const float* __restrict__ b, u16* __restrict__ h1)
{
  int i = blockIdx.x;
  if (i < 3072)       wt_body(w_attn, wt_attn, 1024, 3072, i & 31, i >> 5);
  else if (i < 4096)  { int j = i - 3072; wt_body(w_proj, wt_proj, 1024, 1024, j & 31, j >> 5); }
  else if (i < 8192)  { int j = i - 4096; wt_body(w_fc,   wt_fc,   1024, 4096, j & 31, j >> 5); }
  else if (i < 12288) { int j = i - 8192; wt_body(w_fc2,  wt_fc2,  4096, 1024, j & 127, j >> 7); }
  else                ln_body(x, g, b, h1, i - 12288);
}

// ---------------- layernorm (standalone, for LN2) ---------------------------
__global__ __launch_bounds__(256) void ln_k(const float* __restrict__ x,
                                            const float* __restrict__ g,
                                            const float* __restrict__ bta,
                                            u16* __restrict__ out) {
  ln_body(x, g, bta, out, blockIdx.x);
}

// ---------------- GEMM: C = A[M,K(lda)]bf16 @ Bt[N,K(lda)]^T + epilogue -----
// Single-buffered 2-barrier K-loop (R9-proven). MI=4 (TM=128) for big GEMMs,
// MI=2 for N=1024 GEMMs. XCD-chunked block swizzle (T1): HW maps dispatch-id
// %8 -> XCD, so logical = (orig%8)*(nwg/8)+orig/8 gives each XCD a contiguous
// tile range (same-XCD blocks share B panels -> L2 reuse). Bijective iff
// nwg%8==0 (all our grids: 1024/768/512/512); identity fallback otherwise.
// MODE 0: bf16=v+b  1/3: f32=v+b+resid  2: bf16=gelu(v+b)
// MODE 4: qkv fused epilogue -- cols<1024: bf16=(v+b)*QSCALE -> out;
//         cols 1024..2047 (K): bf16=v+b -> out; cols>=2048 (V): write
//         TRANSPOSED to vtb[(t>>11)*1024 + (col-2048)][t&2047] (packed 8B).
// MODE 5: split-K partial bf16
template<int MODE, int MI, int LB>
__global__ __launch_bounds__(256, LB) void gemm_k(
    const u16* __restrict__ A, const u16* __restrict__ Bt,
    const float* __restrict__ bias, const float* __restrict__ resid,
    void* __restrict__ out, int M, int N, int K, int lda,
    u16* __restrict__ vtb)
{
  constexpr int TM = MI * 32;
  __shared__ u16 Al[TM * 64];
  __shared__ u16 Bl[128 * 64];
  const int tid = threadIdx.x;
  // XCD-chunked swizzle
  const int gx = gridDim.x;
  const int nwg = gx * gridDim.y;
  const int orig = blockIdx.y * gx + blockIdx.x;
  const int lg = ((nwg & 7) == 0) ? ((orig & 7) * (nwg >> 3) + (orig >> 3))
                                  : orig;
  const int bx  = lg % gx;
  const int byl = lg / gx;
  const int sp = (MODE == 5) ? (byl >> 3) : 0;
  const int n0 = (MODE == 5) ? ((byl & 7) * 128) : (byl * 128);
  const size_t koff = (size_t)sp * K;
  const int m0 = bx * TM;
  const int wave = tid >> 6, lane = tid & 63;
  const int wm = (wave >> 1) * (MI * 16), wn = (wave & 1) * 64;
  const int l15 = lane & 15, quad = lane >> 4;
  const int sr = lane >> 3, cs = lane & 7;
  f32x4 acc[MI][4];
  const f32x4 zero = {0.f, 0.f, 0.f, 0.f};
  #pragma unroll
  for (int i = 0; i < MI; ++i)
    #pragma unroll
    for (int j = 0; j < 4; ++j)
      acc[i][j] = zero;
  for (int k0 = 0; k0 < K; k0 += 64) {
    __syncthreads();
    #pragma unroll
    for (int it = 0; it < MI; ++it) {
      int r = it*32 + wave*8 + sr;
      int c = cs ^ (r & 7);
      glds16(&A[(size_t)(m0 + r) * lda + koff + k0 + c*8], &Al[(it*32 + wave*8) * 64]);
    }
    #pragma unroll
    for (int it = 0; it < 4; ++it) {
      int r = it*32 + wave*8 + sr;
      int c = cs ^ (r & 7);
      glds16(&Bt[(size_t)(n0 + r) * lda + koff + k0 + c*8], &Bl[(it*32 + wave*8) * 64]);
    }
    __syncthreads();
    #pragma unroll
    for (int kk = 0; kk < 2; ++kk) {
      bf16x8 af[MI], bfr[4];
      #pragma unroll
      for (int i = 0; i < MI; ++i) {
        int R = wm + i*16 + l15;
        af[i] = *(const bf16x8*)&Al[R*64 + ((kk*4 + quad) ^ (R & 7)) * 8];
      }
      #pragma unroll
      for (int j = 0; j < 4; ++j) {
        int R = wn + j*16 + l15;
        bfr[j] = *(const bf16x8*)&Bl[R*64 + ((kk*4 + quad) ^ (R & 7)) * 8];
      }
      #pragma unroll
      for (int i = 0; i < MI; ++i)
        #pragma unroll
        for (int j = 0; j < 4; ++j)
          acc[i][j] = __builtin_amdgcn_mfma_f32_16x16x32_bf16(af[i], bfr[j], acc[i][j], 0, 0, 0);
    }
  }
  #pragma unroll
  for (int i = 0; i < MI; ++i) {
    #pragma unroll
    for (int j = 0; j < 4; ++j) {
      int col = n0 + wn + j*16 + l15;
      float bv = (MODE == 5) ? 0.f : bias[col];
      if constexpr (MODE == 4) {
        if (col >= 2048) {              // V: write transposed to Vt, packed 8B
          int t0 = m0 + wm + i*16 + quad*4;
          size_t vidx = ((size_t)((t0 >> 11)*1024 + (col - 2048)))*2048 + (t0 & 2047);
          uint2 pw;
          pw.x = pack2(acc[i][j][0] + bv, acc[i][j][1] + bv);
          pw.y = pack2(acc[i][j][2] + bv, acc[i][j][3] + bv);
          *(uint2*)&vtb[vidx] = pw;
          continue;
        }
      }
      float sc = (MODE == 4 && col < 1024) ? QSCALE : 1.0f;
      #pragma unroll
      for (int r = 0; r < 4; ++r) {
        int row = m0 + wm + i*16 + quad*4 + r;
        size_t idx = (size_t)row * N + col;
        float v = acc[i][j][r] + bv;
        if constexpr (MODE == 0)      ((u16*)out)[idx] = bf16r(v);
        else if constexpr (MODE == 1) ((float*)out)[idx] = v + resid[idx];
        else if constexpr (MODE == 2) ((u16*)out)[idx] = bf16r(gelu_f(v));
        else if constexpr (MODE == 4) ((u16*)out)[idx] = bf16r(v * sc);
        else if constexpr (MODE == 5) ((u16*)out)[(size_t)sp*M*N + idx] = bf16r(v);
        else                          ((float*)out)[idx] = v + resid[idx];
      }
    }
  }
}

// ---------------- split-K combine: out = p0 + p1 + bias + x2 (fp32) ---------
__global__ __launch_bounds__(256) void cmb_k(const u16* __restrict__ p,
                                             const float* __restrict__ bias,
                                             const float* __restrict__ x2,
                                             float* __restrict__ out) {
  int row = blockIdx.x, t = threadIdx.x;
  size_t i = (size_t)row * 1024 + t*4;
  uint2 a = *(const uint2*)&p[i];
  uint2 b = *(const uint2*)&p[4194304 + i];
  float4 xv = ((const float4*)x2)[i >> 2];
  float4 bv = ((const float4*)bias)[t];
  float4 o;
  o.x = bf_lo(a.x) + bf_lo(b.x) + bv.x + xv.x;
  o.y = bf_hi(a.x) + bf_hi(b.x) + bv.y + xv.y;
  o.z = bf_lo(a.y) + bf_lo(b.y) + bv.z + xv.z;
  o.w = bf_hi(a.y) + bf_hi(b.y) + bv.w + xv.w;
  ((float4*)out)[i >> 2] = o;
}

// ---------------- MFMA flash attention, S^T, 64-q blocks, fixed-max ---------
// R9-proven shape: grid 1024 = 4 blocks/CU, 64 q-rows/block, single-buffered
// LDS staging for BOTH K and V (25.6KB LDS), heavy q-tiles dispatched first.
// TLP (4 blocks/CU at different loop phases) hides the staging latency.
// DO NOT REVISIT (all measured net-slower): R12 32-q (2x staging passes),
// R20 K/V dbuf (3 blocks/CU, ILP-for-TLP), R22 V-direct-global (uncoalesced
// 4KB-stride dwordx4: 16 cache lines/instr, 4x duplication -> 89us, MfmaUtil
// 7.6%, VMEM-issue bound). The LDS broadcast of V is load-bearing.
__global__ __launch_bounds__(256, 4) void attn_k(const u16* __restrict__ qkv,
                                                 const u16* __restrict__ Vt,
                                                 u16* __restrict__ y) {
  __shared__ u16 Kl[64*64];      // keys x d, XOR-swizzled chunks
  __shared__ u16 Vl[64*64];      // d x keys, XOR-swizzled chunks
  __shared__ u16 Pw[4*16*72];    // per-wave P: 16 q x 64 keys bf16 (+8 pad)
  const int tid = threadIdx.x;
  const int bh = blockIdx.x & 31, bb = bh >> 4, h = bh & 15;
  const int qt = 31 - (int)(blockIdx.x >> 5);   // heavy first
  const int w = tid >> 6, lane = tid & 63;
  const int l15 = lane & 15, quad = lane >> 4;
  const int sr = lane >> 3, cs = lane & 7;
  u16* Pme = Pw + w * (16*72);
  const int w16l = w*16 + l15;
  const int dquad = quad*4;

  const u16* qp = qkv + ((size_t)(bb*2048 + qt*64 + w16l))*3072 + h*64 + quad*8;
  const bf16x8 aq0 = *(const bf16x8*)qp;
  const bf16x8 aq1 = *(const bf16x8*)(qp + 32);

  f32x4 o[4];
  const f32x4 zero = {0.f,0.f,0.f,0.f};
  #pragma unroll
  for (int dt = 0; dt < 4; ++dt) o[dt] = zero;
  float l = 0.f;

  const u16* kbase = qkv + (size_t)bb*2048*3072 + 1024 + h*64;
  const u16* vbase = Vt + (size_t)bh*64*2048;

  for (int kt = 0; kt <= qt; ++kt) {
    __syncthreads();
    #pragma unroll
    for (int it = 0; it < 2; ++it) {
      int r = it*32 + w*8 + sr;
      int c = cs ^ (r & 7);
      glds16(kbase + (size_t)(kt*64 + r)*3072 + c*8, &Kl[(it*32 + w*8) * 64]);
      glds16(vbase + (size_t)r*2048 + kt*64 + c*8,   &Vl[(it*32 + w*8) * 64]);
    }
    __syncthreads();
    bf16x8 ak[4][2], av[4][2];
    #pragma unroll
    for (int nt = 0; nt < 4; ++nt) {
      int R = nt*16 + l15;
      #pragma unroll
      for (int kk = 0; kk < 2; ++kk) {
        ak[nt][kk] = *(const bf16x8*)&Kl[R*64 + ((kk*4 + quad) ^ (R & 7)) * 8];
        av[nt][kk] = *(const bf16x8*)&Vl[R*64 + ((kk*4 + quad) ^ (R & 7)) * 8];
      }
    }
    f32x4 sv[4];
    #pragma unroll
    for (int nt = 0; nt < 4; ++nt) {
      f32x4 s = zero;
      s = __builtin_amdgcn_mfma_f32_16x16x32_bf16(ak[nt][0], aq0, s, 0, 0, 0);
      s = __builtin_amdgcn_mfma_f32_16x16x32_bf16(ak[nt][1], aq1, s, 0, 0, 0);
      sv[nt] = s;
    }
    if (kt == qt) {                           // diagonal tile: causal mask
      #pragma unroll
      for (int nt = 0; nt < 4; ++nt)
        #pragma unroll
        for (int r = 0; r < 4; ++r)
          if (nt*16 + dquad + r > w16l) sv[nt][r] = -1e30f;
    }
    float pv[4][4];
    #pragma unroll
    for (int nt = 0; nt < 4; ++nt)
      #pragma unroll
      for (int r = 0; r < 4; ++r)
        pv[nt][r] = exp2f(sv[nt][r]);         // fixed max=0 (bounded scores)
    l += ((pv[0][0]+pv[0][1])+(pv[0][2]+pv[0][3]))
       + ((pv[1][0]+pv[1][1])+(pv[1][2]+pv[1][3]))
       + ((pv[2][0]+pv[2][1])+(pv[2][2]+pv[2][3]))
       + ((pv[3][0]+pv[3][1])+(pv[3][2]+pv[3][3]));
    #pragma unroll
    for (int nt = 0; nt < 4; ++nt) {
      uint2 pr;
      pr.x = pk_trunc(pv[nt][0], pv[nt][1]);
      pr.y = pk_trunc(pv[nt][2], pv[nt][3]);
      *(uint2*)&Pme[l15*72 + nt*16 + dquad] = pr;
    }
    const bf16x8 bp0 = *(const bf16x8*)&Pme[l15*72 + quad*8];
    const bf16x8 bp1 = *(const bf16x8*)&Pme[l15*72 + 32 + quad*8];
    #pragma unroll
    for (int dt = 0; dt < 4; ++dt) {
      o[dt] = __builtin_amdgcn_mfma_f32_16x16x32_bf16(av[dt][0], bp0, o[dt], 0, 0, 0);
      o[dt] = __builtin_amdgcn_mfma_f32_16x16x32_bf16(av[dt][1], bp1, o[dt], 0, 0, 0);
    }
  }
  float lt = l;
  lt += __shfl_xor(lt, 16);
  lt += __shfl_xor(lt, 32);
  float inv = 1.f / lt;
  u16* yp = y + ((size_t)(bb*2048 + qt*64 + w16l))*1024 + h*64;
  #pragma unroll
  for (int dt = 0; dt < 4; ++dt) {
    uint2 pk;
    pk.x = pack2(o[dt][0]*inv, o[dt][1]*inv);
    pk.y = pack2(o[dt][2]*inv, o[dt][3]*inv);
    *(uint2*)(yp + dt*16 + dquad) = pk;
  }
}

// ---------------------------------------------------------------------------
extern "C" void kernel_launch(void* const* d_in, const int* in_sizes, int n_in,
                              void* d_out, int out_size, void* d_ws, size_t ws_size,
                              hipStream_t stream) {
  const float* x      = (const float*)d_in[0];
  const float* ln1_g  = (const float*)d_in[1];
  const float* ln1_b  = (const float*)d_in[2];
  const float* w_attn = (const float*)d_in[3];
  const float* b_attn = (const float*)d_in[4];
  const float* w_proj = (const float*)d_in[5];
  const float* b_proj = (const float*)d_in[6];
  const float* ln2_g  = (const float*)d_in[7];
  const float* ln2_b  = (const float*)d_in[8];
  const float* w_fc   = (const float*)d_in[9];
  const float* b_fc   = (const float*)d_in[10];
  const float* w_fc2  = (const float*)d_in[11];
  const float* b_fc2  = (const float*)d_in[12];

  char* ws = (char*)d_ws;
  u16*   wt_attn = (u16*)(ws);                 // [3072,1024] bf16 (pk2 alias later)
  u16*   wt_proj = (u16*)(ws + 6291456);       // [1024,1024]
  u16*   wt_fc   = (u16*)(ws + 8388608);       // [4096,1024]
  u16*   wt_fc2  = (u16*)(ws + 16777216);      // [1024,4096]
  u16*   h1      = (u16*)(ws + 25165824);      // [4096,1024] bf16 (h2 alias)
  u16*   qkvb    = (u16*)(ws + 33554432);      // [4096,3072] bf16 (act alias;
                                               //  V third never written/read)
  u16*   yb      = (u16*)(ws + 58720256);      // [4096,1024] bf16
  float* x2      = (float*)(ws + 67108864);    // [4096,1024] f32
  u16*   h2  = h1;
  u16*   vtb = (u16*)(ws + 67108864);          // Vt [32,64,2048] bf16: aliases
                                               //  x2 (dead until proj; proj runs
                                               //  after attn, so clobber is safe)
  u16*   act = qkvb;                           // [4096,4096] bf16
  u16*   pk2 = (u16*)(ws);                     // fc2 partials [2][4096,1024] bf16

  // 4 weight transposes + LN1, one dispatch
  prep_k<<<dim3(16384), 256, 0, stream>>>(w_attn, w_proj, w_fc, w_fc2,
                                          wt_attn, wt_proj, wt_fc, wt_fc2,
                                          x, ln1_g, ln1_b, h1);
  // qkv GEMM with fused V-transpose epilogue
  gemm_k<4,4,3><<<dim3(32, 24), 256, 0, stream>>>(h1, wt_attn, b_attn, nullptr,
      (void*)qkvb, 4096, 3072, 1024, 1024, vtb);
  attn_k<<<dim3(1024), 256, 0, stream>>>(qkvb, vtb, yb);
  gemm_k<1,2,3><<<dim3(64, 8), 256, 0, stream>>>(yb, wt_proj, b_proj, x,
      (void*)x2, 4096, 1024, 1024, 1024, nullptr);
  ln_k<<<4096, 256, 0, stream>>>(x2, ln2_g, ln2_b, h2);
  gemm_k<2,4,3><<<dim3(32, 32), 256, 0, stream>>>(h2, wt_fc, b_fc, nullptr,
      (void*)act, 4096, 4096, 1024, 1024, nullptr);
  // fc2 split-K=2, MI=4 (TM=128): 2x the A-reuse per staged B panel vs MI=2
  gemm_k<5,4,3><<<dim3(32, 16), 256, 0, stream>>>(act, wt_fc2, b_fc2, nullptr,
      (void*)pk2, 4096, 1024, 2048, 4096, nullptr);
  cmb_k<<<4096, 256, 0, stream>>>(pk2, b_fc2, x2, (float*)d_out);
}

// Round 8
// 322.045 us; speedup vs baseline: 1.1496x; 1.0002x over previous
//
#include <hip/hip_runtime.h>

typedef unsigned short u16;
typedef unsigned int   u32;
typedef short bf16x8 __attribute__((ext_vector_type(8)));
typedef float f32x4  __attribute__((ext_vector_type(4)));

__device__ __forceinline__ float bf_lo(u32 u){ return __uint_as_float(u << 16); }
__device__ __forceinline__ float bf_hi(u32 u){ return __uint_as_float(u & 0xffff0000u); }
__device__ __forceinline__ u16 bf16r(float f){
  u32 u = __float_as_uint(f);
  u += 0x7fffu + ((u >> 16) & 1u);
  return (u16)(u >> 16);
}
__device__ __forceinline__ u32 pack2(float a, float b){
  return (u32)bf16r(a) | ((u32)bf16r(b) << 16);
}
// truncating bf16 pair-pack (relative err 2^-8, fine for P in [0,1])
__device__ __forceinline__ u32 pk_trunc(float a, float b){
  return (__float_as_uint(a) >> 16) | (__float_as_uint(b) & 0xffff0000u);
}
__device__ __forceinline__ float gelu_f(float x){
  float t = 0.7978845608028654f * (x + 0.044715f * x * x * x);
  t = fminf(fmaxf(t, -12.f), 12.f);
  float e = __expf(2.f * t);
  float th = (e - 1.f) / (e + 1.f);
  return 0.5f * x * (1.f + th);
}
// async global->LDS, 16B/lane; LDS dest = wave-uniform base + lane*16 (m104)
__device__ __forceinline__ void glds16(const void* g, void* l) {
  __builtin_amdgcn_global_load_lds(
      (const __attribute__((address_space(1))) void*)g,
      (__attribute__((address_space(3))) void*)l, 16, 0, 0);
}

#define QSCALE 0.1803368801111204f   /* 0.125 * log2(e): scores in exp2 domain */

// ---------------- prep bodies (merged into one dispatch) --------------------
__device__ __forceinline__ void wt_body(const float* __restrict__ W,
                                        u16* __restrict__ Wt, int K, int N,
                                        int kx, int nx) {
  __shared__ float t[32][33];
  int k0 = kx * 32, n0 = nx * 32;
  int tx = threadIdx.x & 31, ty = threadIdx.x >> 5;
  #pragma unroll
  for (int i = 0; i < 32; i += 8)
    t[ty + i][tx] = W[(size_t)(k0 + ty + i) * N + n0 + tx];
  __syncthreads();
  #pragma unroll
  for (int i = 0; i < 32; i += 8)
    Wt[(size_t)(n0 + ty + i) * K + k0 + tx] = bf16r(t[tx][ty + i]);
}

__device__ __forceinline__ void ln_body(const float* __restrict__ x,
                                        const float* __restrict__ g,
                                        const float* __restrict__ bta,
                                        u16* __restrict__ out, int row) {
  int tid = threadIdx.x;
  const float4 xv = ((const float4*)(x + (size_t)row * 1024))[tid];
  float s = xv.x + xv.y + xv.z + xv.w;
  float q = xv.x*xv.x + xv.y*xv.y + xv.z*xv.z + xv.w*xv.w;
  #pragma unroll
  for (int off = 32; off > 0; off >>= 1) {
    s += __shfl_down(s, off);
    q += __shfl_down(q, off);
  }
  __shared__ float ss[4], sq[4];
  if ((tid & 63) == 0) { ss[tid >> 6] = s; sq[tid >> 6] = q; }
  __syncthreads();
  s = ss[0] + ss[1] + ss[2] + ss[3];
  q = sq[0] + sq[1] + sq[2] + sq[3];
  float mu = s * (1.f/1024.f);
  float rs = rsqrtf(q * (1.f/1024.f) - mu*mu + 1e-5f);
  const float4 gv = ((const float4*)g)[tid];
  const float4 bv = ((const float4*)bta)[tid];
  uint2 o;
  o.x = pack2((xv.x-mu)*rs*gv.x + bv.x, (xv.y-mu)*rs*gv.y + bv.y);
  o.y = pack2((xv.z-mu)*rs*gv.z + bv.z, (xv.w-mu)*rs*gv.w + bv.w);
  ((uint2*)(out + (size_t)row * 1024))[tid] = o;
}

// all 4 weight transposes + LN1 in one flat-grid dispatch
__global__ __launch_bounds__(256) void prep_k(
    const float* __restrict__ w_attn, const float* __restrict__ w_proj,
    const float* __restrict__ w_fc,   const float* __restrict__ w_fc2,
    u16* __restrict__ wt_attn, u16* __restrict__ wt_proj,
    u16* __restrict__ wt_fc,   u16* __restrict__ wt_fc2,
    const float* __restrict__ x, const float* __restrict__ g,
    const float* __restrict__ b, u16* __restrict__ h1)
{
  int i = blockIdx.x;
  if (i < 3072)       wt_body(w_attn, wt_attn, 1024, 3072, i & 31, i >> 5);
  else if (i < 4096)  { int j = i - 3072; wt_body(w_proj, wt_proj, 1024, 1024, j & 31, j >> 5); }
  else if (i < 8192)  { int j = i - 4096; wt_body(w_fc,   wt_fc,   1024, 4096, j & 31, j >> 5); }
  else if (i < 12288) { int j = i - 8192; wt_body(w_fc2,  wt_fc2,  4096, 1024, j & 127, j >> 7); }
  else                ln_body(x, g, b, h1, i - 12288);
}

// ---------------- layernorm (standalone, for LN2) ---------------------------
__global__ __launch_bounds__(256) void ln_k(const float* __restrict__ x,
                                            const float* __restrict__ g,
                                            const float* __restrict__ bta,
                                            u16* __restrict__ out) {
  ln_body(x, g, bta, out, blockIdx.x);
}

// ---------------- GEMM: C = A[M,K(lda)]bf16 @ Bt[N,K(lda)]^T + epilogue -----
// Single-buffered 2-barrier K-loop (R9-proven). MI=4 (TM=128) for big GEMMs,
// MI=2 for N=1024 GEMMs. Default block order (NO XCD swizzle).
// DO NOT REVISIT (counter-evidenced failures on these K=1024 shapes):
//  - XCD-chunked swizzle (R7): fc FETCH 37.7->56.0 MB, dur 45.5->48.4us.
//    Default round-robin already L2-partitions these small panels; chunked
//    remap put all 32 A-panels (8.4MB) in each XCD's working set -> thrash.
//  - 8-phase 256^2 pipelined schedule (R1/R2-style, two variants): both 26%
//    MfmaUtil vs 30% here; at 1 block/CU the barrier stalls lose the m114
//    cross-block overlap that 3 blocks/CU provides.
//  - Bigger tiles at this structure (m105/m112): 128x256/256^2 < 128^2.
// MODE 0: bf16=v+b  1/3: f32=v+b+resid  2: bf16=gelu(v+b)
// MODE 4: qkv fused epilogue -- cols<1024: bf16=(v+b)*QSCALE -> out;
//         cols 1024..2047 (K): bf16=v+b -> out; cols>=2048 (V): write
//         TRANSPOSED to vtb[(t>>11)*1024 + (col-2048)][t&2047] (packed 8B).
// MODE 5: split-K partial bf16
template<int MODE, int MI, int LB>
__global__ __launch_bounds__(256, LB) void gemm_k(
    const u16* __restrict__ A, const u16* __restrict__ Bt,
    const float* __restrict__ bias, const float* __restrict__ resid,
    void* __restrict__ out, int M, int N, int K, int lda,
    u16* __restrict__ vtb)
{
  constexpr int TM = MI * 32;
  __shared__ u16 Al[TM * 64];
  __shared__ u16 Bl[128 * 64];
  const int tid = threadIdx.x;
  const int by = blockIdx.y;
  const int sp = (MODE == 5) ? (by >> 3) : 0;
  const int n0 = (MODE == 5) ? ((by & 7) * 128) : (by * 128);
  const size_t koff = (size_t)sp * K;
  const int m0 = blockIdx.x * TM;
  const int wave = tid >> 6, lane = tid & 63;
  const int wm = (wave >> 1) * (MI * 16), wn = (wave & 1) * 64;
  const int l15 = lane & 15, quad = lane >> 4;
  const int sr = lane >> 3, cs = lane & 7;
  f32x4 acc[MI][4];
  const f32x4 zero = {0.f, 0.f, 0.f, 0.f};
  #pragma unroll
  for (int i = 0; i < MI; ++i)
    #pragma unroll
    for (int j = 0; j < 4; ++j)
      acc[i][j] = zero;
  for (int k0 = 0; k0 < K; k0 += 64) {
    __syncthreads();
    #pragma unroll
    for (int it = 0; it < MI; ++it) {
      int r = it*32 + wave*8 + sr;
      int c = cs ^ (r & 7);
      glds16(&A[(size_t)(m0 + r) * lda + koff + k0 + c*8], &Al[(it*32 + wave*8) * 64]);
    }
    #pragma unroll
    for (int it = 0; it < 4; ++it) {
      int r = it*32 + wave*8 + sr;
      int c = cs ^ (r & 7);
      glds16(&Bt[(size_t)(n0 + r) * lda + koff + k0 + c*8], &Bl[(it*32 + wave*8) * 64]);
    }
    __syncthreads();
    #pragma unroll
    for (int kk = 0; kk < 2; ++kk) {
      bf16x8 af[MI], bfr[4];
      #pragma unroll
      for (int i = 0; i < MI; ++i) {
        int R = wm + i*16 + l15;
        af[i] = *(const bf16x8*)&Al[R*64 + ((kk*4 + quad) ^ (R & 7)) * 8];
      }
      #pragma unroll
      for (int j = 0; j < 4; ++j) {
        int R = wn + j*16 + l15;
        bfr[j] = *(const bf16x8*)&Bl[R*64 + ((kk*4 + quad) ^ (R & 7)) * 8];
      }
      #pragma unroll
      for (int i = 0; i < MI; ++i)
        #pragma unroll
        for (int j = 0; j < 4; ++j)
          acc[i][j] = __builtin_amdgcn_mfma_f32_16x16x32_bf16(af[i], bfr[j], acc[i][j], 0, 0, 0);
    }
  }
  #pragma unroll
  for (int i = 0; i < MI; ++i) {
    #pragma unroll
    for (int j = 0; j < 4; ++j) {
      int col = n0 + wn + j*16 + l15;
      float bv = (MODE == 5) ? 0.f : bias[col];
      if constexpr (MODE == 4) {
        if (col >= 2048) {              // V: write transposed to Vt, packed 8B
          int t0 = m0 + wm + i*16 + quad*4;
          size_t vidx = ((size_t)((t0 >> 11)*1024 + (col - 2048)))*2048 + (t0 & 2047);
          uint2 pw;
          pw.x = pack2(acc[i][j][0] + bv, acc[i][j][1] + bv);
          pw.y = pack2(acc[i][j][2] + bv, acc[i][j][3] + bv);
          *(uint2*)&vtb[vidx] = pw;
          continue;
        }
      }
      float sc = (MODE == 4 && col < 1024) ? QSCALE : 1.0f;
      #pragma unroll
      for (int r = 0; r < 4; ++r) {
        int row = m0 + wm + i*16 + quad*4 + r;
        size_t idx = (size_t)row * N + col;
        float v = acc[i][j][r] + bv;
        if constexpr (MODE == 0)      ((u16*)out)[idx] = bf16r(v);
        else if constexpr (MODE == 1) ((float*)out)[idx] = v + resid[idx];
        else if constexpr (MODE == 2) ((u16*)out)[idx] = bf16r(gelu_f(v));
        else if constexpr (MODE == 4) ((u16*)out)[idx] = bf16r(v * sc);
        else if constexpr (MODE == 5) ((u16*)out)[(size_t)sp*M*N + idx] = bf16r(v);
        else                          ((float*)out)[idx] = v + resid[idx];
      }
    }
  }
}

// ---------------- split-K combine: out = p0 + p1 + bias + x2 (fp32) ---------
__global__ __launch_bounds__(256) void cmb_k(const u16* __restrict__ p,
                                             const float* __restrict__ bias,
                                             const float* __restrict__ x2,
                                             float* __restrict__ out) {
  int row = blockIdx.x, t = threadIdx.x;
  size_t i = (size_t)row * 1024 + t*4;
  uint2 a = *(const uint2*)&p[i];
  uint2 b = *(const uint2*)&p[4194304 + i];
  float4 xv = ((const float4*)x2)[i >> 2];
  float4 bv = ((const float4*)bias)[t];
  float4 o;
  o.x = bf_lo(a.x) + bf_lo(b.x) + bv.x + xv.x;
  o.y = bf_hi(a.x) + bf_hi(b.x) + bv.y + xv.y;
  o.z = bf_lo(a.y) + bf_lo(b.y) + bv.z + xv.z;
  o.w = bf_hi(a.y) + bf_hi(b.y) + bv.w + xv.w;
  ((float4*)out)[i >> 2] = o;
}

// ---------------- MFMA flash attention, S^T, 64-q blocks, fixed-max ---------
// R9-proven shape: grid 1024 = 4 blocks/CU, 64 q-rows/block, single-buffered
// LDS staging for BOTH K and V (25.6KB LDS), heavy q-tiles dispatched first.
// TLP (4 blocks/CU at different loop phases) hides the staging latency.
// DO NOT REVISIT (all measured net-slower): R12 32-q (2x staging passes),
// R20 K/V dbuf (3 blocks/CU, ILP-for-TLP), R22 V-direct-global (uncoalesced
// 4KB-stride dwordx4: 16 cache lines/instr, 4x duplication -> 89us, MfmaUtil
// 7.6%, VMEM-issue bound). The LDS broadcast of V is load-bearing.
__global__ __launch_bounds__(256, 4) void attn_k(const u16* __restrict__ qkv,
                                                 const u16* __restrict__ Vt,
                                                 u16* __restrict__ y) {
  __shared__ u16 Kl[64*64];      // keys x d, XOR-swizzled chunks
  __shared__ u16 Vl[64*64];      // d x keys, XOR-swizzled chunks
  __shared__ u16 Pw[4*16*72];    // per-wave P: 16 q x 64 keys bf16 (+8 pad)
  const int tid = threadIdx.x;
  const int bh = blockIdx.x & 31, bb = bh >> 4, h = bh & 15;
  const int qt = 31 - (int)(blockIdx.x >> 5);   // heavy first
  const int w = tid >> 6, lane = tid & 63;
  const int l15 = lane & 15, quad = lane >> 4;
  const int sr = lane >> 3, cs = lane & 7;
  u16* Pme = Pw + w * (16*72);
  const int w16l = w*16 + l15;
  const int dquad = quad*4;

  const u16* qp = qkv + ((size_t)(bb*2048 + qt*64 + w16l))*3072 + h*64 + quad*8;
  const bf16x8 aq0 = *(const bf16x8*)qp;
  const bf16x8 aq1 = *(const bf16x8*)(qp + 32);

  f32x4 o[4];
  const f32x4 zero = {0.f,0.f,0.f,0.f};
  #pragma unroll
  for (int dt = 0; dt < 4; ++dt) o[dt] = zero;
  float l = 0.f;

  const u16* kbase = qkv + (size_t)bb*2048*3072 + 1024 + h*64;
  const u16* vbase = Vt + (size_t)bh*64*2048;

  for (int kt = 0; kt <= qt; ++kt) {
    __syncthreads();
    #pragma unroll
    for (int it = 0; it < 2; ++it) {
      int r = it*32 + w*8 + sr;
      int c = cs ^ (r & 7);
      glds16(kbase + (size_t)(kt*64 + r)*3072 + c*8, &Kl[(it*32 + w*8) * 64]);
      glds16(vbase + (size_t)r*2048 + kt*64 + c*8,   &Vl[(it*32 + w*8) * 64]);
    }
    __syncthreads();
    bf16x8 ak[4][2], av[4][2];
    #pragma unroll
    for (int nt = 0; nt < 4; ++nt) {
      int R = nt*16 + l15;
      #pragma unroll
      for (int kk = 0; kk < 2; ++kk) {
        ak[nt][kk] = *(const bf16x8*)&Kl[R*64 + ((kk*4 + quad) ^ (R & 7)) * 8];
        av[nt][kk] = *(const bf16x8*)&Vl[R*64 + ((kk*4 + quad) ^ (R & 7)) * 8];
      }
    }
    f32x4 sv[4];
    #pragma unroll
    for (int nt = 0; nt < 4; ++nt) {
      f32x4 s = zero;
      s = __builtin_amdgcn_mfma_f32_16x16x32_bf16(ak[nt][0], aq0, s, 0, 0, 0);
      s = __builtin_amdgcn_mfma_f32_16x16x32_bf16(ak[nt][1], aq1, s, 0, 0, 0);
      sv[nt] = s;
    }
    if (kt == qt) {                           // diagonal tile: causal mask
      #pragma unroll
      for (int nt = 0; nt < 4; ++nt)
        #pragma unroll
        for (int r = 0; r < 4; ++r)
          if (nt*16 + dquad + r > w16l) sv[nt][r] = -1e30f;
    }
    float pv[4][4];
    #pragma unroll
    for (int nt = 0; nt < 4; ++nt)
      #pragma unroll
      for (int r = 0; r < 4; ++r)
        pv[nt][r] = exp2f(sv[nt][r]);         // fixed max=0 (bounded scores)
    l += ((pv[0][0]+pv[0][1])+(pv[0][2]+pv[0][3]))
       + ((pv[1][0]+pv[1][1])+(pv[1][2]+pv[1][3]))
       + ((pv[2][0]+pv[2][1])+(pv[2][2]+pv[2][3]))
       + ((pv[3][0]+pv[3][1])+(pv[3][2]+pv[3][3]));
    #pragma unroll
    for (int nt = 0; nt < 4; ++nt) {
      uint2 pr;
      pr.x = pk_trunc(pv[nt][0], pv[nt][1]);
      pr.y = pk_trunc(pv[nt][2], pv[nt][3]);
      *(uint2*)&Pme[l15*72 + nt*16 + dquad] = pr;
    }
    const bf16x8 bp0 = *(const bf16x8*)&Pme[l15*72 + quad*8];
    const bf16x8 bp1 = *(const bf16x8*)&Pme[l15*72 + 32 + quad*8];
    #pragma unroll
    for (int dt = 0; dt < 4; ++dt) {
      o[dt] = __builtin_amdgcn_mfma_f32_16x16x32_bf16(av[dt][0], bp0, o[dt], 0, 0, 0);
      o[dt] = __builtin_amdgcn_mfma_f32_16x16x32_bf16(av[dt][1], bp1, o[dt], 0, 0, 0);
    }
  }
  float lt = l;
  lt += __shfl_xor(lt, 16);
  lt += __shfl_xor(lt, 32);
  float inv = 1.f / lt;
  u16* yp = y + ((size_t)(bb*2048 + qt*64 + w16l))*1024 + h*64;
  #pragma unroll
  for (int dt = 0; dt < 4; ++dt) {
    uint2 pk;
    pk.x = pack2(o[dt][0]*inv, o[dt][1]*inv);
    pk.y = pack2(o[dt][2]*inv, o[dt][3]*inv);
    *(uint2*)(yp + dt*16 + dquad) = pk;
  }
}

// ---------------------------------------------------------------------------
extern "C" void kernel_launch(void* const* d_in, const int* in_sizes, int n_in,
                              void* d_out, int out_size, void* d_ws, size_t ws_size,
                              hipStream_t stream) {
  const float* x      = (const float*)d_in[0];
  const float* ln1_g  = (const float*)d_in[1];
  const float* ln1_b  = (const float*)d_in[2];
  const float* w_attn = (const float*)d_in[3];
  const float* b_attn = (const float*)d_in[4];
  const float* w_proj = (const float*)d_in[5];
  const float* b_proj = (const float*)d_in[6];
  const float* ln2_g  = (const float*)d_in[7];
  const float* ln2_b  = (const float*)d_in[8];
  const float* w_fc   = (const float*)d_in[9];
  const float* b_fc   = (const float*)d_in[10];
  const float* w_fc2  = (const float*)d_in[11];
  const float* b_fc2  = (const float*)d_in[12];

  char* ws = (char*)d_ws;
  u16*   wt_attn = (u16*)(ws);                 // [3072,1024] bf16 (pk2 alias later)
  u16*   wt_proj = (u16*)(ws + 6291456);       // [1024,1024]
  u16*   wt_fc   = (u16*)(ws + 8388608);       // [4096,1024]
  u16*   wt_fc2  = (u16*)(ws + 16777216);      // [1024,4096]
  u16*   h1      = (u16*)(ws + 25165824);      // [4096,1024] bf16 (h2 alias)
  u16*   qkvb    = (u16*)(ws + 33554432);      // [4096,3072] bf16 (act alias;
                                               //  V third never written/read)
  u16*   yb      = (u16*)(ws + 58720256);      // [4096,1024] bf16
  float* x2      = (float*)(ws + 67108864);    // [4096,1024] f32
  u16*   h2  = h1;
  u16*   vtb = (u16*)(ws + 67108864);          // Vt [32,64,2048] bf16: aliases
                                               //  x2 (dead until proj; proj runs
                                               //  after attn, so clobber is safe)
  u16*   act = qkvb;                           // [4096,4096] bf16
  u16*   pk2 = (u16*)(ws);                     // fc2 partials [2][4096,1024] bf16

  // 4 weight transposes + LN1, one dispatch
  prep_k<<<dim3(16384), 256, 0, stream>>>(w_attn, w_proj, w_fc, w_fc2,
                                          wt_attn, wt_proj, wt_fc, wt_fc2,
                                          x, ln1_g, ln1_b, h1);
  // qkv GEMM with fused V-transpose epilogue
  gemm_k<4,4,3><<<dim3(32, 24), 256, 0, stream>>>(h1, wt_attn, b_attn, nullptr,
      (void*)qkvb, 4096, 3072, 1024, 1024, vtb);
  attn_k<<<dim3(1024), 256, 0, stream>>>(qkvb, vtb, yb);
  gemm_k<1,2,3><<<dim3(64, 8), 256, 0, stream>>>(yb, wt_proj, b_proj, x,
      (void*)x2, 4096, 1024, 1024, 1024, nullptr);
  ln_k<<<4096, 256, 0, stream>>>(x2, ln2_g, ln2_b, h2);
  gemm_k<2,4,3><<<dim3(32, 32), 256, 0, stream>>>(h2, wt_fc, b_fc, nullptr,
      (void*)act, 4096, 4096, 1024, 1024, nullptr);
  // fc2 split-K=2, MI=4 (TM=128): 2x the A-reuse per staged B panel vs MI=2
  // (R19 A/B: fc2 dropped out of the 45us top-5 band at MI=4 — keep)
  gemm_k<5,4,3><<<dim3(32, 16), 256, 0, stream>>>(act, wt_fc2, b_fc2, nullptr,
      (void*)pk2, 4096, 1024, 2048, 4096, nullptr);
  cmb_k<<<4096, 256, 0, stream>>>(pk2, b_fc2, x2, (float*)d_out);
}

// Round 11
// 305.536 us; speedup vs baseline: 1.2117x; 1.0540x over previous
//
#include <hip/hip_runtime.h>

typedef unsigned short u16;
typedef unsigned int   u32;
typedef short bf16x8 __attribute__((ext_vector_type(8)));
typedef float f32x4  __attribute__((ext_vector_type(4)));

__device__ __forceinline__ float bf_lo(u32 u){ return __uint_as_float(u << 16); }
__device__ __forceinline__ float bf_hi(u32 u){ return __uint_as_float(u & 0xffff0000u); }
__device__ __forceinline__ u16 bf16r(float f){
  u32 u = __float_as_uint(f);
  u += 0x7fffu + ((u >> 16) & 1u);
  return (u16)(u >> 16);
}
__device__ __forceinline__ u32 pack2(float a, float b){
  return (u32)bf16r(a) | ((u32)bf16r(b) << 16);
}
// truncating bf16 pair-pack (relative err 2^-8, fine for P in [0,1])
__device__ __forceinline__ u32 pk_trunc(float a, float b){
  return (__float_as_uint(a) >> 16) | (__float_as_uint(b) & 0xffff0000u);
}
__device__ __forceinline__ float gelu_f(float x){
  float t = 0.7978845608028654f * (x + 0.044715f * x * x * x);
  t = fminf(fmaxf(t, -12.f), 12.f);
  float e = __expf(2.f * t);
  float th = (e - 1.f) / (e + 1.f);
  return 0.5f * x * (1.f + th);
}
// async global->LDS, 16B/lane; LDS dest = wave-uniform base + lane*16 (m104)
__device__ __forceinline__ void glds16(const void* g, void* l) {
  __builtin_amdgcn_global_load_lds(
      (const __attribute__((address_space(1))) void*)g,
      (__attribute__((address_space(3))) void*)l, 16, 0, 0);
}

#define QSCALE 0.1803368801111204f   /* 0.125 * log2(e): scores in exp2 domain */

// ---------------- prep bodies (merged into one dispatch) --------------------
__device__ __forceinline__ void wt_body(const float* __restrict__ W,
                                        u16* __restrict__ Wt, int K, int N,
                                        int kx, int nx) {
  __shared__ float t[32][33];
  int k0 = kx * 32, n0 = nx * 32;
  int tx = threadIdx.x & 31, ty = threadIdx.x >> 5;
  #pragma unroll
  for (int i = 0; i < 32; i += 8)
    t[ty + i][tx] = W[(size_t)(k0 + ty + i) * N + n0 + tx];
  __syncthreads();
  #pragma unroll
  for (int i = 0; i < 32; i += 8)
    Wt[(size_t)(n0 + ty + i) * K + k0 + tx] = bf16r(t[tx][ty + i]);
}

__device__ __forceinline__ void ln_body(const float* __restrict__ x,
                                        const float* __restrict__ g,
                                        const float* __restrict__ bta,
                                        u16* __restrict__ out, int row) {
  int tid = threadIdx.x;
  const float4 xv = ((const float4*)(x + (size_t)row * 1024))[tid];
  float s = xv.x + xv.y + xv.z + xv.w;
  float q = xv.x*xv.x + xv.y*xv.y + xv.z*xv.z + xv.w*xv.w;
  #pragma unroll
  for (int off = 32; off > 0; off >>= 1) {
    s += __shfl_down(s, off);
    q += __shfl_down(q, off);
  }
  __shared__ float ss[4], sq[4];
  if ((tid & 63) == 0) { ss[tid >> 6] = s; sq[tid >> 6] = q; }
  __syncthreads();
  s = ss[0] + ss[1] + ss[2] + ss[3];
  q = sq[0] + sq[1] + sq[2] + sq[3];
  float mu = s * (1.f/1024.f);
  float rs = rsqrtf(q * (1.f/1024.f) - mu*mu + 1e-5f);
  const float4 gv = ((const float4*)g)[tid];
  const float4 bv = ((const float4*)bta)[tid];
  uint2 o;
  o.x = pack2((xv.x-mu)*rs*gv.x + bv.x, (xv.y-mu)*rs*gv.y + bv.y);
  o.y = pack2((xv.z-mu)*rs*gv.z + bv.z, (xv.w-mu)*rs*gv.w + bv.w);
  ((uint2*)(out + (size_t)row * 1024))[tid] = o;
}

// all 4 weight transposes + LN1 in one flat-grid dispatch
__global__ __launch_bounds__(256) void prep_k(
    const float* __restrict__ w_attn, const float* __restrict__ w_proj,
    const float* __restrict__ w_fc,   const float* __restrict__ w_fc2,
    u16* __restrict__ wt_attn, u16* __restrict__ wt_proj,
    u16* __restrict__ wt_fc,   u16* __restrict__ wt_fc2,
    const float* __restrict__ x, const float* __restrict__ g,
    const float* __restrict__ b, u16* __restrict__ h1)
{
  int i = blockIdx.x;
  if (i < 3072)       wt_body(w_attn, wt_attn, 1024, 3072, i & 31, i >> 5);
  else if (i < 4096)  { int j = i - 3072; wt_body(w_proj, wt_proj, 1024, 1024, j & 31, j >> 5); }
  else if (i < 8192)  { int j = i - 4096; wt_body(w_fc,   wt_fc,   1024, 4096, j & 31, j >> 5); }
  else if (i < 12288) { int j = i - 8192; wt_body(w_fc2,  wt_fc2,  4096, 1024, j & 127, j >> 7); }
  else                ln_body(x, g, b, h1, i - 12288);
}

// ---------------- layernorm (standalone, for LN2) ---------------------------
__global__ __launch_bounds__(256) void ln_k(const float* __restrict__ x,
                                            const float* __restrict__ g,
                                            const float* __restrict__ bta,
                                            u16* __restrict__ out) {
  ln_body(x, g, bta, out, blockIdx.x);
}

// ---------------- GEMM: C = A[M,K(lda)]bf16 @ Bt[N,K(lda)]^T + epilogue -----
// Single-buffered 2-barrier K-loop (R9-proven). MI=4 (TM=128) for big GEMMs,
// MI=2 for N=1024 GEMMs. Default block order (NO XCD swizzle).
// LB=4 on the 1024-block fc grid (R26): 4 blocks/CU -> whole grid
// co-resident, no straggler round (m114 cross-block overlap is this kernel's
// proven stall-hiding mechanism). VGPR 64 <= 128-cap, 4x32KB LDS <= 160KB.
// DO NOT REVISIT (counter- or audit-evidenced failures on these shapes):
//  - XCD-chunked swizzle (R7): fc FETCH 37.7->56.0 MB, dur 45.5->48.4us.
//  - 8-phase 256^2 pipelined schedule (two variants): 26% MfmaUtil vs 30%.
//  - Bigger tiles at this structure (m105/m112): 128x256/256^2 < 128^2.
//  - fc2 split-K=4 (R9/R10): needs 4 dead 8.39MB partial regions; act spans
//    [33.5MB, 67.1MB) and swallows yb, so only 3 exist -> pk3=yb raced with
//    the act reads (absmax 0.297). Split-K=2 with partials in [0,16.7MB) is
//    the only safe placement. Also: split count x K' must equal full K
//    (R9: K'=512 summed half the range, absmax 1.9).
//  - Cross-round dur_us deltas <15us are clock noise (R5 vs R8: identical
//    code, 306.9 vs 322.0). Judge by within-profile counters.
// MODE 0: bf16=v+b  1/3: f32=v+b+resid  2: bf16=gelu(v+b)
// MODE 4: qkv fused epilogue -- cols<1024: bf16=(v+b)*QSCALE -> out;
//         cols 1024..2047 (K): bf16=v+b -> out; cols>=2048 (V): write
//         TRANSPOSED to vtb[(t>>11)*1024 + (col-2048)][t&2047] (packed 8B).
// MODE 5: split-K=2 partial bf16 -> out[sp*M*N + idx]
template<int MODE, int MI, int LB>
__global__ __launch_bounds__(256, LB) void gemm_k(
    const u16* __restrict__ A, const u16* __restrict__ Bt,
    const float* __restrict__ bias, const float* __restrict__ resid,
    void* __restrict__ out, int M, int N, int K, int lda,
    u16* __restrict__ vtb)
{
  constexpr int TM = MI * 32;
  __shared__ u16 Al[TM * 64];
  __shared__ u16 Bl[128 * 64];
  const int tid = threadIdx.x;
  const int by = blockIdx.y;
  const int sp = (MODE == 5) ? (by >> 3) : 0;
  const int n0 = (MODE == 5) ? ((by & 7) * 128) : (by * 128);
  const size_t koff = (size_t)sp * K;
  const int m0 = blockIdx.x * TM;
  const int wave = tid >> 6, lane = tid & 63;
  const int wm = (wave >> 1) * (MI * 16), wn = (wave & 1) * 64;
  const int l15 = lane & 15, quad = lane >> 4;
  const int sr = lane >> 3, cs = lane & 7;
  f32x4 acc[MI][4];
  const f32x4 zero = {0.f, 0.f, 0.f, 0.f};
  #pragma unroll
  for (int i = 0; i < MI; ++i)
    #pragma unroll
    for (int j = 0; j < 4; ++j)
      acc[i][j] = zero;
  for (int k0 = 0; k0 < K; k0 += 64) {
    __syncthreads();
    #pragma unroll
    for (int it = 0; it < MI; ++it) {
      int r = it*32 + wave*8 + sr;
      int c = cs ^ (r & 7);
      glds16(&A[(size_t)(m0 + r) * lda + koff + k0 + c*8], &Al[(it*32 + wave*8) * 64]);
    }
    #pragma unroll
    for (int it = 0; it < 4; ++it) {
      int r = it*32 + wave*8 + sr;
      int c = cs ^ (r & 7);
      glds16(&Bt[(size_t)(n0 + r) * lda + koff + k0 + c*8], &Bl[(it*32 + wave*8) * 64]);
    }
    __syncthreads();
    #pragma unroll
    for (int kk = 0; kk < 2; ++kk) {
      bf16x8 af[MI], bfr[4];
      #pragma unroll
      for (int i = 0; i < MI; ++i) {
        int R = wm + i*16 + l15;
        af[i] = *(const bf16x8*)&Al[R*64 + ((kk*4 + quad) ^ (R & 7)) * 8];
      }
      #pragma unroll
      for (int j = 0; j < 4; ++j) {
        int R = wn + j*16 + l15;
        bfr[j] = *(const bf16x8*)&Bl[R*64 + ((kk*4 + quad) ^ (R & 7)) * 8];
      }
      #pragma unroll
      for (int i = 0; i < MI; ++i)
        #pragma unroll
        for (int j = 0; j < 4; ++j)
          acc[i][j] = __builtin_amdgcn_mfma_f32_16x16x32_bf16(af[i], bfr[j], acc[i][j], 0, 0, 0);
    }
  }
  #pragma unroll
  for (int i = 0; i < MI; ++i) {
    #pragma unroll
    for (int j = 0; j < 4; ++j) {
      int col = n0 + wn + j*16 + l15;
      float bv = (MODE == 5) ? 0.f : bias[col];
      if constexpr (MODE == 4) {
        if (col >= 2048) {              // V: write transposed to Vt, packed 8B
          int t0 = m0 + wm + i*16 + quad*4;
          size_t vidx = ((size_t)((t0 >> 11)*1024 + (col - 2048)))*2048 + (t0 & 2047);
          uint2 pw;
          pw.x = pack2(acc[i][j][0] + bv, acc[i][j][1] + bv);
          pw.y = pack2(acc[i][j][2] + bv, acc[i][j][3] + bv);
          *(uint2*)&vtb[vidx] = pw;
          continue;
        }
      }
      float sc = (MODE == 4 && col < 1024) ? QSCALE : 1.0f;
      #pragma unroll
      for (int r = 0; r < 4; ++r) {
        int row = m0 + wm + i*16 + quad*4 + r;
        size_t idx = (size_t)row * N + col;
        float v = acc[i][j][r] + bv;
        if constexpr (MODE == 0)      ((u16*)out)[idx] = bf16r(v);
        else if constexpr (MODE == 1) ((float*)out)[idx] = v + resid[idx];
        else if constexpr (MODE == 2) ((u16*)out)[idx] = bf16r(gelu_f(v));
        else if constexpr (MODE == 4) ((u16*)out)[idx] = bf16r(v * sc);
        else if constexpr (MODE == 5) ((u16*)out)[(size_t)sp*M*N + idx] = bf16r(v);
        else                          ((float*)out)[idx] = v + resid[idx];
      }
    }
  }
}

// ---------------- split-K combine: out = p0 + p1 + bias + x2 (fp32) ---------
__global__ __launch_bounds__(256) void cmb_k(const u16* __restrict__ p,
                                             const float* __restrict__ bias,
                                             const float* __restrict__ x2,
                                             float* __restrict__ out) {
  int row = blockIdx.x, t = threadIdx.x;
  size_t i = (size_t)row * 1024 + t*4;
  uint2 a = *(const uint2*)&p[i];
  uint2 b = *(const uint2*)&p[4194304 + i];
  float4 xv = ((const float4*)x2)[i >> 2];
  float4 bv = ((const float4*)bias)[t];
  float4 o;
  o.x = bf_lo(a.x) + bf_lo(b.x) + bv.x + xv.x;
  o.y = bf_hi(a.x) + bf_hi(b.x) + bv.y + xv.y;
  o.z = bf_lo(a.y) + bf_lo(b.y) + bv.z + xv.z;
  o.w = bf_hi(a.y) + bf_hi(b.y) + bv.w + xv.w;
  ((float4*)out)[i >> 2] = o;
}

// ---------------- MFMA flash attention, S^T, 64-q blocks, fixed-max ---------
// R9-proven shape: grid 1024 = 4 blocks/CU, 64 q-rows/block, single-buffered
// LDS staging for BOTH K and V (25.6KB LDS), heavy q-tiles dispatched first.
// TLP (4 blocks/CU at different loop phases) hides the staging latency.
// DO NOT REVISIT (all measured net-slower): R12 32-q (2x staging passes),
// R20 K/V dbuf (3 blocks/CU, ILP-for-TLP), R22 V-direct-global (uncoalesced
// 4KB-stride dwordx4: 16 cache lines/instr, 4x duplication -> 89us, MfmaUtil
// 7.6%, VMEM-issue bound). The LDS broadcast of V is load-bearing.
__global__ __launch_bounds__(256, 4) void attn_k(const u16* __restrict__ qkv,
                                                 const u16* __restrict__ Vt,
                                                 u16* __restrict__ y) {
  __shared__ u16 Kl[64*64];      // keys x d, XOR-swizzled chunks
  __shared__ u16 Vl[64*64];      // d x keys, XOR-swizzled chunks
  __shared__ u16 Pw[4*16*72];    // per-wave P: 16 q x 64 keys bf16 (+8 pad)
  const int tid = threadIdx.x;
  const int bh = blockIdx.x & 31, bb = bh >> 4, h = bh & 15;
  const int qt = 31 - (int)(blockIdx.x >> 5);   // heavy first
  const int w = tid >> 6, lane = tid & 63;
  const int l15 = lane & 15, quad = lane >> 4;
  const int sr = lane >> 3, cs = lane & 7;
  u16* Pme = Pw + w * (16*72);
  const int w16l = w*16 + l15;
  const int dquad = quad*4;

  const u16* qp = qkv + ((size_t)(bb*2048 + qt*64 + w16l))*3072 + h*64 + quad*8;
  const bf16x8 aq0 = *(const bf16x8*)qp;
  const bf16x8 aq1 = *(const bf16x8*)(qp + 32);

  f32x4 o[4];
  const f32x4 zero = {0.f,0.f,0.f,0.f};
  #pragma unroll
  for (int dt = 0; dt < 4; ++dt) o[dt] = zero;
  float l = 0.f;

  const u16* kbase = qkv + (size_t)bb*2048*3072 + 1024 + h*64;
  const u16* vbase = Vt + (size_t)bh*64*2048;

  for (int kt = 0; kt <= qt; ++kt) {
    __syncthreads();
    #pragma unroll
    for (int it = 0; it < 2; ++it) {
      int r = it*32 + w*8 + sr;
      int c = cs ^ (r & 7);
      glds16(kbase + (size_t)(kt*64 + r)*3072 + c*8, &Kl[(it*32 + w*8) * 64]);
      glds16(vbase + (size_t)r*2048 + kt*64 + c*8,   &Vl[(it*32 + w*8) * 64]);
    }
    __syncthreads();
    bf16x8 ak[4][2], av[4][2];
    #pragma unroll
    for (int nt = 0; nt < 4; ++nt) {
      int R = nt*16 + l15;
      #pragma unroll
      for (int kk = 0; kk < 2; ++kk) {
        ak[nt][kk] = *(const bf16x8*)&Kl[R*64 + ((kk*4 + quad) ^ (R & 7)) * 8];
        av[nt][kk] = *(const bf16x8*)&Vl[R*64 + ((kk*4 + quad) ^ (R & 7)) * 8];
      }
    }
    f32x4 sv[4];
    #pragma unroll
    for (int nt = 0; nt < 4; ++nt) {
      f32x4 s = zero;
      s = __builtin_amdgcn_mfma_f32_16x16x32_bf16(ak[nt][0], aq0, s, 0, 0, 0);
      s = __builtin_amdgcn_mfma_f32_16x16x32_bf16(ak[nt][1], aq1, s, 0, 0, 0);
      sv[nt] = s;
    }
    if (kt == qt) {                           // diagonal tile: causal mask
      #pragma unroll
      for (int nt = 0; nt < 4; ++nt)
        #pragma unroll
        for (int r = 0; r < 4; ++r)
          if (nt*16 + dquad + r > w16l) sv[nt][r] = -1e30f;
    }
    float pv[4][4];
    #pragma unroll
    for (int nt = 0; nt < 4; ++nt)
      #pragma unroll
      for (int r = 0; r < 4; ++r)
        pv[nt][r] = exp2f(sv[nt][r]);         // fixed max=0 (bounded scores)
    l += ((pv[0][0]+pv[0][1])+(pv[0][2]+pv[0][3]))
       + ((pv[1][0]+pv[1][1])+(pv[1][2]+pv[1][3]))
       + ((pv[2][0]+pv[2][1])+(pv[2][2]+pv[2][3]))
       + ((pv[3][0]+pv[3][1])+(pv[3][2]+pv[3][3]));
    #pragma unroll
    for (int nt = 0; nt < 4; ++nt) {
      uint2 pr;
      pr.x = pk_trunc(pv[nt][0], pv[nt][1]);
      pr.y = pk_trunc(pv[nt][2], pv[nt][3]);
      *(uint2*)&Pme[l15*72 + nt*16 + dquad] = pr;
    }
    const bf16x8 bp0 = *(const bf16x8*)&Pme[l15*72 + quad*8];
    const bf16x8 bp1 = *(const bf16x8*)&Pme[l15*72 + 32 + quad*8];
    #pragma unroll
    for (int dt = 0; dt < 4; ++dt) {
      o[dt] = __builtin_amdgcn_mfma_f32_16x16x32_bf16(av[dt][0], bp0, o[dt], 0, 0, 0);
      o[dt] = __builtin_amdgcn_mfma_f32_16x16x32_bf16(av[dt][1], bp1, o[dt], 0, 0, 0);
    }
  }
  float lt = l;
  lt += __shfl_xor(lt, 16);
  lt += __shfl_xor(lt, 32);
  float inv = 1.f / lt;
  u16* yp = y + ((size_t)(bb*2048 + qt*64 + w16l))*1024 + h*64;
  #pragma unroll
  for (int dt = 0; dt < 4; ++dt) {
    uint2 pk;
    pk.x = pack2(o[dt][0]*inv, o[dt][1]*inv);
    pk.y = pack2(o[dt][2]*inv, o[dt][3]*inv);
    *(uint2*)(yp + dt*16 + dquad) = pk;
  }
}

// ---------------------------------------------------------------------------
extern "C" void kernel_launch(void* const* d_in, const int* in_sizes, int n_in,
                              void* d_out, int out_size, void* d_ws, size_t ws_size,
                              hipStream_t stream) {
  const float* x      = (const float*)d_in[0];
  const float* ln1_g  = (const float*)d_in[1];
  const float* ln1_b  = (const float*)d_in[2];
  const float* w_attn = (const float*)d_in[3];
  const float* b_attn = (const float*)d_in[4];
  const float* w_proj = (const float*)d_in[5];
  const float* b_proj = (const float*)d_in[6];
  const float* ln2_g  = (const float*)d_in[7];
  const float* ln2_b  = (const float*)d_in[8];
  const float* w_fc   = (const float*)d_in[9];
  const float* b_fc   = (const float*)d_in[10];
  const float* w_fc2  = (const float*)d_in[11];
  const float* b_fc2  = (const float*)d_in[12];

  char* ws = (char*)d_ws;
  u16*   wt_attn = (u16*)(ws);                 // [3072,1024] bf16 (pk alias later)
  u16*   wt_proj = (u16*)(ws + 6291456);       // [1024,1024]
  u16*   wt_fc   = (u16*)(ws + 8388608);       // [4096,1024]
  u16*   wt_fc2  = (u16*)(ws + 16777216);      // [1024,4096]  (alive thru fc2)
  u16*   h1      = (u16*)(ws + 25165824);      // [4096,1024] bf16 (h2 alias)
  u16*   qkvb    = (u16*)(ws + 33554432);      // [4096,3072] bf16 (act alias;
                                               //  V third never written/read)
  u16*   yb      = (u16*)(ws + 58720256);      // [4096,1024] bf16 (inside act!)
  float* x2      = (float*)(ws + 67108864);    // [4096,1024] f32
  u16*   h2  = h1;
  u16*   vtb = (u16*)(ws + 67108864);          // Vt [32,64,2048] bf16: aliases
                                               //  x2 (dead until proj; proj runs
                                               //  after attn, so clobber is safe)
  u16*   act = qkvb;                           // [4096,4096] bf16 = [33.5,67.1)MB
  u16*   pk2 = (u16*)(ws);                     // fc2 partials [2][4096,1024] bf16
                                               //  = [0,16.7MB): wt_attn+wt_proj+
                                               //  wt_fc, all dead post-fc. The
                                               //  ONLY regions disjoint from act.

  // 4 weight transposes + LN1, one dispatch
  prep_k<<<dim3(16384), 256, 0, stream>>>(w_attn, w_proj, w_fc, w_fc2,
                                          wt_attn, wt_proj, wt_fc, wt_fc2,
                                          x, ln1_g, ln1_b, h1);
  // qkv GEMM with fused V-transpose epilogue (768 blocks = 3/CU; LB=4 benign)
  gemm_k<4,4,4><<<dim3(32, 24), 256, 0, stream>>>(h1, wt_attn, b_attn, nullptr,
      (void*)qkvb, 4096, 3072, 1024, 1024, vtb);
  attn_k<<<dim3(1024), 256, 0, stream>>>(qkvb, vtb, yb);
  gemm_k<1,2,3><<<dim3(64, 8), 256, 0, stream>>>(yb, wt_proj, b_proj, x,
      (void*)x2, 4096, 1024, 1024, 1024, nullptr);
  ln_k<<<4096, 256, 0, stream>>>(x2, ln2_g, ln2_b, h2);
  // fc GEMM: 1024 blocks, LB=4 -> whole grid co-resident (no straggler round)
  gemm_k<2,4,4><<<dim3(32, 32), 256, 0, stream>>>(h2, wt_fc, b_fc, nullptr,
      (void*)act, 4096, 4096, 1024, 1024, nullptr);
  // fc2: PROVEN split-K=2 (K'=2048), partials in [0,16.7MB); LB=4 benign
  gemm_k<5,4,4><<<dim3(32, 16), 256, 0, stream>>>(act, wt_fc2, b_fc2, nullptr,
      (void*)pk2, 4096, 1024, 2048, 4096, nullptr);
  cmb_k<<<4096, 256, 0, stream>>>(pk2, b_fc2, x2, (float*)d_out);
}